// Round 1
// baseline (222.351 us; speedup 1.0000x reference)
//
#include <hip/hip_runtime.h>
#include <hip/hip_bf16.h>

// Deformable 3D conv: B=2, CIN=COUT=64, D=8,H=32,W=32, K=27 (3x3x3), stride=1,pad=1,dil=1
// Strategy: fused sample->bf16->MFMA GEMM. Out[64 x 8192] = W[64 x 1728] * S[1728 x 8192] per batch.
// Pre-kernel converts weight to bf16 [k][o][c] layout in d_ws (221 KB).

#define BB    2
#define CINC  64
#define COUTC 64
#define DDEP  8
#define HGT   32
#define WID   32
#define KK    27
#define PP    8192      // DOUT*HOUT*WOUT = 8*32*32
#define TP    64        // output positions per workgroup
#define LDW   72        // padded LDS row stride (bf16 elems): 2-way-free frag reads

typedef short s16x8 __attribute__((ext_vector_type(8)));
typedef float f32x4 __attribute__((ext_vector_type(4)));

__device__ __forceinline__ unsigned short f2bf(float f) {
    unsigned u = __builtin_bit_cast(unsigned, f);
    u += 0x7FFFu + ((u >> 16) & 1u);   // RNE
    return (unsigned short)(u >> 16);
}

// weight (COUT, CIN, 27) fp32 -> wt[(k*64+o)*64+c] bf16
__global__ void wt_kernel(const float* __restrict__ w, unsigned short* __restrict__ wt) {
    int id = blockIdx.x * 256 + threadIdx.x;
    if (id >= KK * COUTC * CINC) return;
    int c = id & 63;
    int o = (id >> 6) & 63;
    int k = id >> 12;
    wt[id] = f2bf(w[(o * CINC + c) * KK + k]);
}

// trilinear sample: 4 (d,h)-corner pairs, each contributes pair.x*A0+pair.y*A1 along w
__device__ __forceinline__ float samp(const float* __restrict__ cp, const int4 vi,
                                      const float4 bc, float A0, float A1) {
    float x0 = cp[vi.x], y0 = cp[vi.x + 1];
    float x1 = cp[vi.y], y1 = cp[vi.y + 1];
    float x2 = cp[vi.z], y2 = cp[vi.z + 1];
    float x3 = cp[vi.w], y3 = cp[vi.w + 1];
    float ax = bc.x * x0 + bc.y * x1 + bc.z * x2 + bc.w * x3;
    float ay = bc.x * y0 + bc.y * y1 + bc.z * y2 + bc.w * y3;
    return A0 * ax + A1 * ay;
}

__global__ __launch_bounds__(256, 1) void deform_kernel(
    const float* __restrict__ x, const float* __restrict__ off,
    const unsigned short* __restrict__ wt, const float* __restrict__ bias,
    float* __restrict__ out)
{
    __shared__ unsigned short sW[COUTC * LDW] __attribute__((aligned(16))); // [o][c] bf16
    __shared__ unsigned short sS[TP * LDW]    __attribute__((aligned(16))); // [p][c] bf16
    __shared__ int   sIdx[TP][4] __attribute__((aligned(16)));
    __shared__ float sCf[TP][8]  __attribute__((aligned(32)));

    const int t    = threadIdx.x;
    const int lane = t & 63;
    const int wv   = t >> 6;           // wave 0..3
    const int blk  = blockIdx.x;       // 0..255
    const int b    = blk >> 7;
    const int p0   = (blk & 127) * TP;

    const float* xb = x + b * CINC * PP;

    f32x4 acc[4];
    #pragma unroll
    for (int f = 0; f < 4; ++f) acc[f] = (f32x4)0.0f;

    const int n0 = lane & 15;
    const int q  = lane >> 4;

    #pragma unroll 1
    for (int k = 0; k < KK; ++k) {
        // ---- stage weight tile sW[o][c] (coalesced 16B loads)
        const unsigned short* wk = wt + k * (COUTC * CINC);
        #pragma unroll
        for (int j = 0; j < 2; ++j) {
            int idx = j * 2048 + t * 8;
            *(s16x8*)&sW[(idx >> 6) * LDW + (idx & 63)] = *(const s16x8*)(wk + idx);
        }

        // ---- per-position coords/weights (validity fused into trilinear weights)
        if (t < TP) {
            int pp = p0 + t;
            int ow = pp & 31;
            int oh = (pp >> 5) & 31;
            int od = pp >> 10;
            int kd = k / 9;
            int kh = (k - kd * 9) / 3;
            int kw = k - kd * 9 - kh * 3;
            const float* ob = off + (size_t)(b * (3 * KK) + 3 * k) * PP + pp;
            float zd = (float)(od - 1 + kd) + ob[0];
            float zh = (float)(oh - 1 + kh) + ob[PP];
            float zw = (float)(ow - 1 + kw) + ob[2 * PP];

            float fdf = floorf(zd); int d0 = (int)fdf; float fd = zd - fdf;
            float fhf = floorf(zh); int h0 = (int)fhf; float fh = zh - fhf;
            float fwf = floorf(zw); int w0 = (int)fwf; float fw = zw - fwf;

            float Bd0 = (d0 >= 0     && d0 < DDEP)     ? 1.0f - fd : 0.0f;
            float Bd1 = (d0 + 1 >= 0 && d0 + 1 < DDEP) ? fd        : 0.0f;
            float Ch0 = (h0 >= 0     && h0 < HGT)      ? 1.0f - fh : 0.0f;
            float Ch1 = (h0 + 1 >= 0 && h0 + 1 < HGT)  ? fh        : 0.0f;
            int dc0 = min(max(d0, 0), DDEP - 1);
            int dc1 = min(max(d0 + 1, 0), DDEP - 1);
            int hc0 = min(max(h0, 0), HGT - 1);
            int hc1 = min(max(h0 + 1, 0), HGT - 1);

            // w handled as aligned-safe pair load at wb=clamp(w0,0,30):
            // A0/A1 = effective weights for pair.x / pair.y (OOB folded in)
            int wb = min(max(w0, 0), WID - 2);
            int e0 = w0 - wb;                       // 0 normally; 1 if w0==31; -1 if w0==-1
            bool v0 = (w0 >= 0)  && (w0 < WID);
            bool v1 = (w0 >= -1) && (w0 < WID - 1);
            float A0 = 0.0f, A1 = 0.0f;
            if (v0) { if (e0 == 0) A0 += 1.0f - fw; else A1 += 1.0f - fw; }
            if (v1) { if (e0 == 0) A1 += fw;        else A0 += fw; }

            sIdx[t][0] = (dc0 * HGT + hc0) * WID + wb;
            sIdx[t][1] = (dc0 * HGT + hc1) * WID + wb;
            sIdx[t][2] = (dc1 * HGT + hc0) * WID + wb;
            sIdx[t][3] = (dc1 * HGT + hc1) * WID + wb;
            sCf[t][0] = Bd0 * Ch0;
            sCf[t][1] = Bd0 * Ch1;
            sCf[t][2] = Bd1 * Ch0;
            sCf[t][3] = Bd1 * Ch1;
            sCf[t][4] = A0;
            sCf[t][5] = A1;
        }
        __syncthreads();

        // ---- sampling: thread handles p=lane, c in [wv*16, wv*16+16)  (c wave-uniform)
        {
            int4   vidx = *(const int4*)&sIdx[lane][0];
            float4 bc   = *(const float4*)&sCf[lane][0];
            float  A0   = sCf[lane][4];
            float  A1   = sCf[lane][5];
            const float* cb = xb + (wv * 16) * PP;
            #pragma unroll
            for (int cc = 0; cc < 16; cc += 2) {
                float s0 = samp(cb + cc * PP,       vidx, bc, A0, A1);
                float s1 = samp(cb + (cc + 1) * PP, vidx, bc, A0, A1);
                unsigned pk = (unsigned)f2bf(s0) | ((unsigned)f2bf(s1) << 16);
                *(unsigned*)&sS[lane * LDW + wv * 16 + cc] = pk;
            }
        }
        __syncthreads();

        // ---- MFMA: wave wv -> output rows [16*wv,16*wv+16), all 64 cols (4 n-frags), Kdim=64 (2 steps)
        {
            s16x8 a0 = *(const s16x8*)&sW[(16 * wv + n0) * LDW +      8 * q];
            s16x8 a1 = *(const s16x8*)&sW[(16 * wv + n0) * LDW + 32 + 8 * q];
            #pragma unroll
            for (int f = 0; f < 4; ++f) {
                s16x8 b0 = *(const s16x8*)&sS[(16 * f + n0) * LDW +      8 * q];
                s16x8 b1 = *(const s16x8*)&sS[(16 * f + n0) * LDW + 32 + 8 * q];
                acc[f] = __builtin_amdgcn_mfma_f32_16x16x32_bf16(a0, b0, acc[f], 0, 0, 0);
                acc[f] = __builtin_amdgcn_mfma_f32_16x16x32_bf16(a1, b1, acc[f], 0, 0, 0);
            }
        }
        __syncthreads();
    }

    // ---- epilogue: C/D layout col=lane&15, row=(lane>>4)*4+r
    float bv[4];
    #pragma unroll
    for (int r = 0; r < 4; ++r) bv[r] = bias[16 * wv + 4 * q + r];
    #pragma unroll
    for (int f = 0; f < 4; ++f) {
        #pragma unroll
        for (int r = 0; r < 4; ++r) {
            int o = 16 * wv + 4 * q + r;
            int p = p0 + 16 * f + n0;
            out[(b * COUTC + o) * PP + p] = acc[f][r] + bv[r];
        }
    }
}

extern "C" void kernel_launch(void* const* d_in, const int* in_sizes, int n_in,
                              void* d_out, int out_size, void* d_ws, size_t ws_size,
                              hipStream_t stream) {
    const float* x    = (const float*)d_in[0];
    const float* off  = (const float*)d_in[1];
    const float* w    = (const float*)d_in[2];
    const float* bias = (const float*)d_in[3];
    float* out        = (float*)d_out;
    unsigned short* wt = (unsigned short*)d_ws;   // needs 27*64*64*2 = 221184 B

    hipLaunchKernelGGL(wt_kernel, dim3((KK * COUTC * CINC + 255) / 256), dim3(256), 0, stream,
                       w, wt);
    hipLaunchKernelGGL(deform_kernel, dim3(BB * (PP / TP)), dim3(256), 0, stream,
                       x, off, wt, bias, out);
}

// Round 2
// 147.586 us; speedup vs baseline: 1.5066x; 1.5066x over previous
//
#include <hip/hip_runtime.h>
#include <hip/hip_bf16.h>

// Deformable 3D conv: B=2, CIN=COUT=64, D=8,H=32,W=32, K=27 (3x3x3), stride=1,pad=1,dil=1
// Round 2: (a) pre-transpose x -> xt[b][dhw][c] so trilinear corner gathers are
// coalesced (lane=c, 256B per corner per wave); (b) split K=27 into 3 groups of 9
// across blockIdx.y (3 blocks/CU, 12 waves/CU) with fp32 atomic accumulation.

#define BB    2
#define CINC  64
#define COUTC 64
#define DDEP  8
#define HGT   32
#define WID   32
#define KK    27
#define KGRP  3
#define KPG   9         // k's per group
#define PP    8192      // DOUT*HOUT*WOUT = 8*32*32
#define TP    64        // output positions per workgroup
#define LDW   72        // padded LDS row stride (bf16 elems)

typedef short s16x8 __attribute__((ext_vector_type(8)));
typedef float f32x4 __attribute__((ext_vector_type(4)));

__device__ __forceinline__ unsigned short f2bf(float f) {
    unsigned u = __builtin_bit_cast(unsigned, f);
    u += 0x7FFFu + ((u >> 16) & 1u);   // RNE
    return (unsigned short)(u >> 16);
}

// Fused pre-kernel:
//  blocks [0,256): transpose x[b][c][s] -> xt[b][s][c]  (64x64 tiles via LDS)
//  blocks [256,688): weight (COUT,CIN,27) fp32 -> wt[(k*64+o)*64+c] bf16
__global__ void pre_kernel(const float* __restrict__ x, const float* __restrict__ w,
                           float* __restrict__ xt, unsigned short* __restrict__ wt) {
    __shared__ float sT[64][65];
    const int t    = threadIdx.x;
    const int lane = t & 63;
    const int wv   = t >> 6;
    int blk = blockIdx.x;
    if (blk < 256) {
        int b  = blk >> 7;
        int s0 = (blk & 127) * 64;
        #pragma unroll
        for (int i = 0; i < 16; ++i) {
            int c = wv * 16 + i;
            sT[c][lane] = x[(size_t)(b * CINC + c) * PP + s0 + lane];
        }
        __syncthreads();
        #pragma unroll
        for (int i = 0; i < 16; ++i) {
            int s = wv * 16 + i;
            xt[(size_t)(b * PP + s0 + s) * 64 + lane] = sT[lane][s];
        }
    } else {
        int id = (blk - 256) * 256 + t;
        if (id < KK * COUTC * CINC) {
            int c = id & 63;
            int o = (id >> 6) & 63;
            int k = id >> 12;
            wt[id] = f2bf(w[(o * CINC + c) * KK + k]);
        }
    }
}

__global__ __launch_bounds__(256, 3) void deform_kernel(
    const float* __restrict__ xt, const float* __restrict__ off,
    const unsigned short* __restrict__ wt, const float* __restrict__ bias,
    float* __restrict__ out)
{
    __shared__ unsigned short sW[COUTC * LDW] __attribute__((aligned(16))); // [o][c] bf16
    __shared__ unsigned short sS[TP * LDW]    __attribute__((aligned(16))); // [p][c] bf16
    __shared__ int   sIdx[TP][8] __attribute__((aligned(32)));  // 8 corner elem-offsets (pre-scaled x64)
    __shared__ float sCf[TP][8]  __attribute__((aligned(32)));  // 8 corner weights (validity folded)

    const int t    = threadIdx.x;
    const int lane = t & 63;
    const int wv   = t >> 6;             // wave 0..3
    const int b    = blockIdx.x >> 7;
    const int p0   = (blockIdx.x & 127) * TP;
    const int kg   = blockIdx.y;         // 0..2

    const float* xtb = xt + (size_t)b * PP * 64 + lane;   // lane = channel

    f32x4 acc[4];
    #pragma unroll
    for (int f = 0; f < 4; ++f) acc[f] = (f32x4)0.0f;

    const int n0 = lane & 15;
    const int q  = lane >> 4;

    #pragma unroll 1
    for (int k = kg * KPG; k < kg * KPG + KPG; ++k) {
        // ---- stage weight tile sW[o][c] (coalesced 16B loads)
        const unsigned short* wk = wt + k * (COUTC * CINC);
        #pragma unroll
        for (int j = 0; j < 2; ++j) {
            int idx = j * 2048 + t * 8;
            *(s16x8*)&sW[(idx >> 6) * LDW + (idx & 63)] = *(const s16x8*)(wk + idx);
        }

        // ---- per-position corner offsets/weights (validity fused into weights)
        if (t < TP) {
            int pp = p0 + t;
            int ow = pp & 31;
            int oh = (pp >> 5) & 31;
            int od = pp >> 10;
            int kd = k / 9;
            int kh = (k - kd * 9) / 3;
            int kw = k - kd * 9 - kh * 3;
            const float* ob = off + (size_t)(b * (3 * KK) + 3 * k) * PP + pp;
            float zd = (float)(od - 1 + kd) + ob[0];
            float zh = (float)(oh - 1 + kh) + ob[PP];
            float zw = (float)(ow - 1 + kw) + ob[2 * PP];

            float fdf = floorf(zd); int d0 = (int)fdf; float fd = zd - fdf;
            float fhf = floorf(zh); int h0 = (int)fhf; float fh = zh - fhf;
            float fwf = floorf(zw); int w0 = (int)fwf; float fw = zw - fwf;

            float Bd0 = (d0 >= 0     && d0 < DDEP)     ? 1.0f - fd : 0.0f;
            float Bd1 = (d0 + 1 >= 0 && d0 + 1 < DDEP) ? fd        : 0.0f;
            float Ch0 = (h0 >= 0     && h0 < HGT)      ? 1.0f - fh : 0.0f;
            float Ch1 = (h0 + 1 >= 0 && h0 + 1 < HGT)  ? fh        : 0.0f;
            float Aw0 = (w0 >= 0     && w0 < WID)      ? 1.0f - fw : 0.0f;
            float Aw1 = (w0 + 1 >= 0 && w0 + 1 < WID)  ? fw        : 0.0f;
            int dc0 = min(max(d0, 0), DDEP - 1);
            int dc1 = min(max(d0 + 1, 0), DDEP - 1);
            int hc0 = min(max(h0, 0), HGT - 1);
            int hc1 = min(max(h0 + 1, 0), HGT - 1);
            int wc0 = min(max(w0, 0), WID - 1);
            int wc1 = min(max(w0 + 1, 0), WID - 1);

            // element offsets into xt[b][s][c], pre-scaled by 64 channels
            int dhb0 = (dc0 * HGT + hc0) * (WID * 64);
            int dhb1 = (dc0 * HGT + hc1) * (WID * 64);
            int dhb2 = (dc1 * HGT + hc0) * (WID * 64);
            int dhb3 = (dc1 * HGT + hc1) * (WID * 64);
            int wo0 = wc0 * 64, wo1 = wc1 * 64;
            sIdx[t][0] = dhb0 + wo0;
            sIdx[t][1] = dhb1 + wo0;
            sIdx[t][2] = dhb2 + wo0;
            sIdx[t][3] = dhb3 + wo0;
            sIdx[t][4] = dhb0 + wo1;
            sIdx[t][5] = dhb1 + wo1;
            sIdx[t][6] = dhb2 + wo1;
            sIdx[t][7] = dhb3 + wo1;
            float bc0 = Bd0 * Ch0, bc1 = Bd0 * Ch1, bc2 = Bd1 * Ch0, bc3 = Bd1 * Ch1;
            sCf[t][0] = bc0 * Aw0;
            sCf[t][1] = bc1 * Aw0;
            sCf[t][2] = bc2 * Aw0;
            sCf[t][3] = bc3 * Aw0;
            sCf[t][4] = bc0 * Aw1;
            sCf[t][5] = bc1 * Aw1;
            sCf[t][6] = bc2 * Aw1;
            sCf[t][7] = bc3 * Aw1;
        }
        __syncthreads();

        // ---- sampling: wave wv handles p in [wv*16, wv*16+16), lane = channel.
        // Each corner load: 64 lanes x 4B contiguous (256B, fully coalesced).
        #pragma unroll 4
        for (int j = 0; j < 16; ++j) {
            int p = wv * 16 + j;
            int4   i0 = *(const int4*)&sIdx[p][0];     // broadcast ds_reads
            int4   i1 = *(const int4*)&sIdx[p][4];
            float4 u0 = *(const float4*)&sCf[p][0];
            float4 u1 = *(const float4*)&sCf[p][4];
            float s = u0.x * xtb[i0.x] + u0.y * xtb[i0.y]
                    + u0.z * xtb[i0.z] + u0.w * xtb[i0.w]
                    + u1.x * xtb[i1.x] + u1.y * xtb[i1.y]
                    + u1.z * xtb[i1.z] + u1.w * xtb[i1.w];
            sS[p * LDW + lane] = f2bf(s);
        }
        __syncthreads();

        // ---- MFMA: wave wv -> output rows [16*wv,16*wv+16), 4 p-frags, Kdim=64 (2 steps)
        {
            s16x8 a0 = *(const s16x8*)&sW[(16 * wv + n0) * LDW +      8 * q];
            s16x8 a1 = *(const s16x8*)&sW[(16 * wv + n0) * LDW + 32 + 8 * q];
            #pragma unroll
            for (int f = 0; f < 4; ++f) {
                s16x8 b0 = *(const s16x8*)&sS[(16 * f + n0) * LDW +      8 * q];
                s16x8 b1 = *(const s16x8*)&sS[(16 * f + n0) * LDW + 32 + 8 * q];
                acc[f] = __builtin_amdgcn_mfma_f32_16x16x32_bf16(a0, b0, acc[f], 0, 0, 0);
                acc[f] = __builtin_amdgcn_mfma_f32_16x16x32_bf16(a1, b1, acc[f], 0, 0, 0);
            }
        }
        __syncthreads();
    }

    // ---- epilogue: atomic-accumulate partial k-group results; bias added by group 0.
    // C/D layout: col=lane&15 (p), row=(lane>>4)*4+r (o)
    float bv[4];
    #pragma unroll
    for (int r = 0; r < 4; ++r) bv[r] = (kg == 0) ? bias[16 * wv + 4 * q + r] : 0.0f;
    #pragma unroll
    for (int f = 0; f < 4; ++f) {
        #pragma unroll
        for (int r = 0; r < 4; ++r) {
            int o = 16 * wv + 4 * q + r;
            int p = p0 + 16 * f + n0;
            unsafeAtomicAdd(&out[(size_t)(b * COUTC + o) * PP + p], acc[f][r] + bv[r]);
        }
    }
}

extern "C" void kernel_launch(void* const* d_in, const int* in_sizes, int n_in,
                              void* d_out, int out_size, void* d_ws, size_t ws_size,
                              hipStream_t stream) {
    const float* x    = (const float*)d_in[0];
    const float* off  = (const float*)d_in[1];
    const float* w    = (const float*)d_in[2];
    const float* bias = (const float*)d_in[3];
    float* out        = (float*)d_out;

    float* xt          = (float*)d_ws;                          // 2*8192*64*4 = 4 MB
    unsigned short* wt = (unsigned short*)((char*)d_ws + (size_t)BB * PP * 64 * 4); // 221184 B

    hipMemsetAsync(out, 0, (size_t)out_size * sizeof(float), stream);
    hipLaunchKernelGGL(pre_kernel, dim3(256 + (KK * COUTC * CINC + 255) / 256), dim3(256), 0,
                       stream, x, w, xt, wt);
    hipLaunchKernelGGL(deform_kernel, dim3(BB * (PP / TP), KGRP), dim3(256), 0, stream,
                       xt, off, wt, bias, out);
}

// Round 4
// 103.346 us; speedup vs baseline: 2.1515x; 1.4281x over previous
//
#include <hip/hip_runtime.h>
#include <hip/hip_bf16.h>

// Deformable 3D conv: B=2, CIN=COUT=64, D=8,H=32,W=32, K=27, stride=1,pad=1,dil=1
// Round 4 = Round 3 with compile fix (manual bf16x2 pack instead of bit_cast of
// __hip_bfloat162): bf16 xt (1 corner = one 128B line); packed 2-channels/lane
// sampling with 2 positions per wave-load; coords for 3 k's batched across 192
// threads; weight tiles staged 3-at-a-time; fully unrolled sampling.

#define BB    2
#define CINC  64
#define COUTC 64
#define DDEP  8
#define HGT   32
#define WID   32
#define KK    27
#define KGRP  3
#define KPG   9         // k's per blockIdx.y group
#define KPH   3         // k's per phase (coord batch)
#define PP    8192      // DOUT*HOUT*WOUT
#define TP    64        // output positions per workgroup
#define LDW   72        // padded LDS row stride (bf16 elems)

typedef short s16x8 __attribute__((ext_vector_type(8)));
typedef float f32x4 __attribute__((ext_vector_type(4)));

__device__ __forceinline__ unsigned short f2bf(float f) {
    unsigned u = __builtin_bit_cast(unsigned, f);
    u += 0x7FFFu + ((u >> 16) & 1u);   // RNE
    return (unsigned short)(u >> 16);
}

__device__ __forceinline__ unsigned pack2bf(float lo, float hi) {
    return (unsigned)f2bf(lo) | ((unsigned)f2bf(hi) << 16);
}

__device__ __forceinline__ float bfu_lo(unsigned v) {
    return __builtin_bit_cast(float, v << 16);
}
__device__ __forceinline__ float bfu_hi(unsigned v) {
    return __builtin_bit_cast(float, v & 0xFFFF0000u);
}

// Fused pre-kernel:
//  blocks [0,256): transpose+convert x[b][c][s] fp32 -> xt[b][s][c] bf16
//  blocks [256,688): weight (COUT,CIN,27) fp32 -> wt[(k*64+o)*64+c] bf16
__global__ void pre_kernel(const float* __restrict__ x, const float* __restrict__ w,
                           unsigned short* __restrict__ xt, unsigned short* __restrict__ wt) {
    __shared__ float sT[64][65];
    const int t    = threadIdx.x;
    const int lane = t & 63;
    const int wv   = t >> 6;
    const int half = lane >> 5;
    const int c2   = lane & 31;
    int blk = blockIdx.x;
    if (blk < 256) {
        int b  = blk >> 7;
        int s0 = (blk & 127) * 64;
        #pragma unroll
        for (int i = 0; i < 16; ++i) {
            int c = wv * 16 + i;
            sT[c][lane] = x[(size_t)(b * CINC + c) * PP + s0 + lane];
        }
        __syncthreads();
        #pragma unroll
        for (int i = 0; i < 8; ++i) {
            int s = wv * 16 + 2 * i + half;
            unsigned pk = pack2bf(sT[2 * c2][s], sT[2 * c2 + 1][s]);
            *(unsigned*)&xt[(size_t)(b * PP + s0 + s) * 64 + 2 * c2] = pk;
        }
    } else {
        int id = (blk - 256) * 256 + t;
        if (id < KK * COUTC * CINC) {
            int c = id & 63;
            int o = (id >> 6) & 63;
            int k = id >> 12;
            wt[id] = f2bf(w[(o * CINC + c) * KK + k]);
        }
    }
}

__global__ __launch_bounds__(256, 3) void deform_kernel(
    const unsigned short* __restrict__ xt, const float* __restrict__ off,
    const unsigned short* __restrict__ wt, const float* __restrict__ bias,
    float* __restrict__ out)
{
    __shared__ unsigned short sW[KPH * COUTC * LDW] __attribute__((aligned(16))); // 3x [o][c]
    __shared__ unsigned short sS[TP * LDW]          __attribute__((aligned(16))); // [p][c]
    __shared__ int   sIdx[KPH][TP][8] __attribute__((aligned(16)));  // corner short-offsets
    __shared__ float sCf[KPH][TP][8]  __attribute__((aligned(16)));  // corner weights

    const int t    = threadIdx.x;
    const int lane = t & 63;
    const int wv   = t >> 6;
    const int half = lane >> 5;          // 0: position pA, 1: position pB
    const int c2   = lane & 31;          // channel pair index
    const int b    = blockIdx.x >> 7;
    const int p0   = (blockIdx.x & 127) * TP;
    const int kg   = blockIdx.y;

    const unsigned short* xb = xt + (size_t)b * PP * 64;

    f32x4 acc[4];
    #pragma unroll
    for (int f = 0; f < 4; ++f) acc[f] = (f32x4)0.0f;

    const int n0 = lane & 15;
    const int q  = lane >> 4;

    #pragma unroll 1
    for (int ph = 0; ph < 3; ++ph) {
        const int kbase = kg * KPG + ph * KPH;

        // ---- stage 3 weight tiles (coalesced 16B loads)
        const unsigned short* wk = wt + kbase * (COUTC * CINC);
        #pragma unroll
        for (int j = 0; j < 6; ++j) {
            int idx = j * 2048 + t * 8;
            int kl  = idx >> 12;
            int rem = idx & 4095;
            *(s16x8*)&sW[kl * (COUTC * LDW) + (rem >> 6) * LDW + (rem & 63)] =
                *(const s16x8*)(wk + idx);
        }

        // ---- coords for 3 k's, 192 threads in parallel (k wave-uniform)
        if (t < KPH * TP) {
            int kl = t >> 6;
            int k  = kbase + kl;
            int pl = t & 63;
            int pp = p0 + pl;
            int ow = pp & 31;
            int oh = (pp >> 5) & 31;
            int od = pp >> 10;
            int kd = k / 9;
            int kh = (k - kd * 9) / 3;
            int kw = k - kd * 9 - kh * 3;
            const float* ob = off + (size_t)(b * (3 * KK) + 3 * k) * PP + pp;
            float zd = (float)(od - 1 + kd) + ob[0];
            float zh = (float)(oh - 1 + kh) + ob[PP];
            float zw = (float)(ow - 1 + kw) + ob[2 * PP];

            float fdf = floorf(zd); int d0 = (int)fdf; float fd = zd - fdf;
            float fhf = floorf(zh); int h0 = (int)fhf; float fh = zh - fhf;
            float fwf = floorf(zw); int w0 = (int)fwf; float fw = zw - fwf;

            float Bd0 = (d0 >= 0     && d0 < DDEP)     ? 1.0f - fd : 0.0f;
            float Bd1 = (d0 + 1 >= 0 && d0 + 1 < DDEP) ? fd        : 0.0f;
            float Ch0 = (h0 >= 0     && h0 < HGT)      ? 1.0f - fh : 0.0f;
            float Ch1 = (h0 + 1 >= 0 && h0 + 1 < HGT)  ? fh        : 0.0f;
            float Aw0 = (w0 >= 0     && w0 < WID)      ? 1.0f - fw : 0.0f;
            float Aw1 = (w0 + 1 >= 0 && w0 + 1 < WID)  ? fw        : 0.0f;
            int dc0 = min(max(d0, 0), DDEP - 1);
            int dc1 = min(max(d0 + 1, 0), DDEP - 1);
            int hc0 = min(max(h0, 0), HGT - 1);
            int hc1 = min(max(h0 + 1, 0), HGT - 1);
            int wc0 = min(max(w0, 0), WID - 1);
            int wc1 = min(max(w0 + 1, 0), WID - 1);

            int dhb0 = (dc0 * HGT + hc0) * (WID * 64);
            int dhb1 = (dc0 * HGT + hc1) * (WID * 64);
            int dhb2 = (dc1 * HGT + hc0) * (WID * 64);
            int dhb3 = (dc1 * HGT + hc1) * (WID * 64);
            int wo0 = wc0 * 64, wo1 = wc1 * 64;
            sIdx[kl][pl][0] = dhb0 + wo0;
            sIdx[kl][pl][1] = dhb1 + wo0;
            sIdx[kl][pl][2] = dhb2 + wo0;
            sIdx[kl][pl][3] = dhb3 + wo0;
            sIdx[kl][pl][4] = dhb0 + wo1;
            sIdx[kl][pl][5] = dhb1 + wo1;
            sIdx[kl][pl][6] = dhb2 + wo1;
            sIdx[kl][pl][7] = dhb3 + wo1;
            float bc0 = Bd0 * Ch0, bc1 = Bd0 * Ch1, bc2 = Bd1 * Ch0, bc3 = Bd1 * Ch1;
            sCf[kl][pl][0] = bc0 * Aw0;
            sCf[kl][pl][1] = bc1 * Aw0;
            sCf[kl][pl][2] = bc2 * Aw0;
            sCf[kl][pl][3] = bc3 * Aw0;
            sCf[kl][pl][4] = bc0 * Aw1;
            sCf[kl][pl][5] = bc1 * Aw1;
            sCf[kl][pl][6] = bc2 * Aw1;
            sCf[kl][pl][7] = bc3 * Aw1;
        }
        __syncthreads();

        #pragma unroll
        for (int kl = 0; kl < KPH; ++kl) {
            // ---- sampling: 8 position-pairs; lanes 0-31 do pA, 32-63 do pB.
            // One wave-load = corner q of both positions (2 x 128B lines).
            #pragma unroll
            for (int jp = 0; jp < 8; ++jp) {
                int prow = wv * 16 + 2 * jp + half;
                const int4   i0 = *(const int4*)&sIdx[kl][prow][0];
                const int4   i1 = *(const int4*)&sIdx[kl][prow][4];
                const float4 u0 = *(const float4*)&sCf[kl][prow][0];
                const float4 u1 = *(const float4*)&sCf[kl][prow][4];
                float slo = 0.0f, shi = 0.0f;
                {
                    unsigned v0 = *(const unsigned*)(xb + i0.x + 2 * c2);
                    unsigned v1 = *(const unsigned*)(xb + i0.y + 2 * c2);
                    unsigned v2 = *(const unsigned*)(xb + i0.z + 2 * c2);
                    unsigned v3 = *(const unsigned*)(xb + i0.w + 2 * c2);
                    unsigned v4 = *(const unsigned*)(xb + i1.x + 2 * c2);
                    unsigned v5 = *(const unsigned*)(xb + i1.y + 2 * c2);
                    unsigned v6 = *(const unsigned*)(xb + i1.z + 2 * c2);
                    unsigned v7 = *(const unsigned*)(xb + i1.w + 2 * c2);
                    slo += u0.x * bfu_lo(v0); shi += u0.x * bfu_hi(v0);
                    slo += u0.y * bfu_lo(v1); shi += u0.y * bfu_hi(v1);
                    slo += u0.z * bfu_lo(v2); shi += u0.z * bfu_hi(v2);
                    slo += u0.w * bfu_lo(v3); shi += u0.w * bfu_hi(v3);
                    slo += u1.x * bfu_lo(v4); shi += u1.x * bfu_hi(v4);
                    slo += u1.y * bfu_lo(v5); shi += u1.y * bfu_hi(v5);
                    slo += u1.z * bfu_lo(v6); shi += u1.z * bfu_hi(v6);
                    slo += u1.w * bfu_lo(v7); shi += u1.w * bfu_hi(v7);
                }
                *(unsigned*)&sS[prow * LDW + 2 * c2] = pack2bf(slo, shi);
            }
            __syncthreads();

            // ---- MFMA: wave wv -> rows [16wv,16wv+16), 4 p-frags, Kdim=64
            {
                const unsigned short* sWk = &sW[kl * (COUTC * LDW)];
                s16x8 a0 = *(const s16x8*)&sWk[(16 * wv + n0) * LDW +      8 * q];
                s16x8 a1 = *(const s16x8*)&sWk[(16 * wv + n0) * LDW + 32 + 8 * q];
                #pragma unroll
                for (int f = 0; f < 4; ++f) {
                    s16x8 b0 = *(const s16x8*)&sS[(16 * f + n0) * LDW +      8 * q];
                    s16x8 b1 = *(const s16x8*)&sS[(16 * f + n0) * LDW + 32 + 8 * q];
                    acc[f] = __builtin_amdgcn_mfma_f32_16x16x32_bf16(a0, b0, acc[f], 0, 0, 0);
                    acc[f] = __builtin_amdgcn_mfma_f32_16x16x32_bf16(a1, b1, acc[f], 0, 0, 0);
                }
            }
            __syncthreads();
        }
    }

    // ---- epilogue: atomic partial accumulate; bias added by kg==0.
    float bv[4];
    #pragma unroll
    for (int r = 0; r < 4; ++r) bv[r] = (kg == 0) ? bias[16 * wv + 4 * q + r] : 0.0f;
    #pragma unroll
    for (int f = 0; f < 4; ++f) {
        #pragma unroll
        for (int r = 0; r < 4; ++r) {
            int o = 16 * wv + 4 * q + r;
            int p = p0 + 16 * f + n0;
            unsafeAtomicAdd(&out[(size_t)(b * COUTC + o) * PP + p], acc[f][r] + bv[r]);
        }
    }
}

extern "C" void kernel_launch(void* const* d_in, const int* in_sizes, int n_in,
                              void* d_out, int out_size, void* d_ws, size_t ws_size,
                              hipStream_t stream) {
    const float* x    = (const float*)d_in[0];
    const float* off  = (const float*)d_in[1];
    const float* w    = (const float*)d_in[2];
    const float* bias = (const float*)d_in[3];
    float* out        = (float*)d_out;

    unsigned short* xt = (unsigned short*)d_ws;                       // 2*8192*64*2 = 2 MB
    unsigned short* wt = (unsigned short*)((char*)d_ws + (size_t)BB * PP * 64 * 2); // 221184 B

    (void)hipMemsetAsync(out, 0, (size_t)out_size * sizeof(float), stream);
    hipLaunchKernelGGL(pre_kernel, dim3(256 + (KK * COUTC * CINC + 255) / 256), dim3(256), 0,
                       stream, x, w, xt, wt);
    hipLaunchKernelGGL(deform_kernel, dim3(BB * (PP / TP), KGRP), dim3(256), 0, stream,
                       xt, off, wt, bias, out);
}